// Round 6
// baseline (96.006 us; speedup 1.0000x reference)
//
#include <hip/hip_runtime.h>
#include <math.h>

// ---------- constants (normalization folded per the reference) ----------
#define SQ15f      3.8729833462074170f   // sqrt(15)
#define C2_XZ      1.7320508075688772f   // sqrt(3)
#define C2_ZX      0.8660254037844386f   // sqrt(3)/2
#define C3_A       0.4082482904638631f   // 1/sqrt(6)
#define C3_B       0.6123724356957945f   // sqrt(24)/8
#define EMB_SCALE  2.8234622000789103f   // sqrt(10)/1.12

typedef float v2f __attribute__((ext_vector_type(2)));
typedef float v4f __attribute__((ext_vector_type(4)));

// Pack pos (Nx rows) and qpos (Nq rows) from 12B rows into 16B rows in ws.
__global__ void pack_kernel(const float* __restrict__ pos,
                            const float* __restrict__ qpos,
                            float* __restrict__ wp, int Nx, int Nq) {
    int i = blockIdx.x * blockDim.x + threadIdx.x;
    if (i < Nx + Nq) {
        const float* src = (i < Nx) ? (pos + 3 * (size_t)i) : (qpos + 3 * (size_t)(i - Nx));
        v4f v = { src[0], src[1], src[2], 0.0f };
        *((v4f*)wp + i) = v;
    }
}

// sh LDS layout: logical in-block float g (0..4095) lives at ssh[g + (g>>4)]
// == row-major [256][16] padded to stride 17 (write stride 17: conflict-free).
// emb LDS layout: plain linear [2560].
template <bool PACKED>
__global__ __launch_bounds__(256)
void fused_kernel(const float* __restrict__ pos,   // packed: 4-stride rows
                  const float* __restrict__ qpos,  // packed: 4-stride rows
                  const float* __restrict__ feat,
                  const int*   __restrict__ esrc,
                  const int*   __restrict__ edst,
                  float* __restrict__ out,
                  int E, int nblk_edge, int n2feat,
                  unsigned long long OFF_SRC, unsigned long long OFF_DST,
                  unsigned long long OFF_EMB, unsigned long long OFF_SH,
                  unsigned long long OFF_LEN) {
    const int tid = threadIdx.x;
    const int blk = blockIdx.x;

    if (blk >= nblk_edge) {                 // ---- feature passthrough blocks ----
        int i = (blk - nblk_edge) * 256 + tid;
        if (i == 0) { out[0] = 10.0f; out[1] = 1000.0f; }   // Nt, Ny
        if (i < n2feat) {
            v2f v = __builtin_nontemporal_load(((const v2f*)feat) + i);
            __builtin_nontemporal_store(v, ((v2f*)(out + 2)) + i);
        }
        return;
    }

    __shared__ float semb[2560];
    __shared__ float ssh [4352];

    const int base = blk * 256;
    const int nb   = min(256, E - base);
    const int e    = base + tid;

    if (tid < nb) {
        int s = __builtin_nontemporal_load(esrc + e);
        int d = __builtin_nontemporal_load(edst + e);

        float vx, vy, vz;
        if (PACKED) {
            v4f Q = *((const v4f*)qpos + s);
            v4f P = *((const v4f*)pos  + d);
            vx = Q.x - P.x; vy = Q.y - P.y; vz = Q.z - P.z;
        } else {
            vx = qpos[3 * s + 0] - pos[3 * d + 0];
            vy = qpos[3 * s + 1] - pos[3 * d + 1];
            vz = qpos[3 * s + 2] - pos[3 * d + 2];
        }

        float ss  = vx * vx + vy * vy + vz * vz;
        float len = sqrtf(ss + 1e-8f);

        float n   = sqrtf(ss);
        float inv = 1.0f / fmaxf(n, 1e-12f);
        float x = vx * inv, y = vy * inv, z = vz * inv;

        float x2 = x * x, y2 = y * y, z2 = z * z;
        float x2z2 = x2 + z2;

        float s20 = SQ15f * x * z;
        float s24 = 0.5f * SQ15f * (z2 - x2);
        float q   = 4.0f * y2 - x2z2;

        float* sh = &ssh[tid * 17];
        sh[0] = 1.0f;
        sh[1] = x;  sh[2] = y;  sh[3] = z;
        sh[4] = C2_XZ * x * z;
        sh[5] = C2_XZ * x * y;
        sh[6] = y2 - 0.5f * x2z2;
        sh[7] = C2_XZ * y * z;
        sh[8] = C2_ZX * (z2 - x2);
        sh[9]  = C3_A * (s20 * z + s24 * x);
        sh[10] = s20 * y;
        sh[11] = C3_B * q * x;
        sh[12] = 0.5f * y * (2.0f * y2 - 3.0f * x2z2);
        sh[13] = C3_B * z * q;
        sh[14] = s24 * y;
        sh[15] = C3_A * (s24 * z - s20 * x);

        float t = (0.2f - len) * 5.5f;
        float cut;
        if (t <= 0.0f)      cut = 1.0f;
        else if (t >= 1.0f) cut = 0.0f;
        else {
            float t2 = t * t;
            float t4 = t2 * t2;
            cut = 1.0f - (5.0f * t4 - 4.0f * t4 * t);
        }
        float cs = cut * EMB_SCALE;

        float* em = &semb[tid * 10];
#pragma unroll
        for (int i = 0; i < 10; ++i) {
            float m  = (9.0f + 8.0f * (float)i) * (1.0f / 81.0f);
            float dd = (len - m) * 9.0f;
            em[i] = __expf(-dd * dd) * cs;
        }

        __builtin_nontemporal_store((float)s, out + OFF_SRC + e);
        __builtin_nontemporal_store((float)d, out + OFF_DST + e);
        __builtin_nontemporal_store(len,      out + OFF_LEN + e);
    }
    __syncthreads();

    float* egb = out + OFF_EMB + (size_t)10 * base;   // base ≡ 2 (mod 4) in floats
    float* sgb = out + OFF_SH  + (size_t)16 * base;

    if (nb == 256) {
        // ---- emb: head v2f + 639 aligned v4f + tail v2f ----
#pragma unroll
        for (int i = 0; i < 3; ++i) {
            int idx = i * 256 + tid;
            if (idx < 639) {
                int p = 2 + 4 * idx;
                v4f v = { semb[p], semb[p + 1], semb[p + 2], semb[p + 3] };
                __builtin_nontemporal_store(v, (v4f*)(egb + p));
            }
        }
        if (tid == 0) { v2f h = { semb[0], semb[1] };        __builtin_nontemporal_store(h, (v2f*)egb); }
        if (tid == 1) { v2f tl = { semb[2558], semb[2559] }; __builtin_nontemporal_store(tl, (v2f*)(egb + 2558)); }

        // ---- sh: head v2f + 1023 aligned v4f + tail v2f ----
#pragma unroll
        for (int i = 0; i < 4; ++i) {
            int idx = i * 256 + tid;
            if (idx < 1023) {
                int g0 = 2 + 4 * idx;
                v4f v = { ssh[g0 + (g0 >> 4)],
                          ssh[(g0 + 1) + ((g0 + 1) >> 4)],
                          ssh[(g0 + 2) + ((g0 + 2) >> 4)],
                          ssh[(g0 + 3) + ((g0 + 3) >> 4)] };
                __builtin_nontemporal_store(v, (v4f*)(sgb + g0));
            }
        }
        if (tid == 2) { v2f h = { ssh[0], ssh[1] };           __builtin_nontemporal_store(h, (v2f*)sgb); }
        if (tid == 3) { v2f tl = { ssh[4349], ssh[4350] };    __builtin_nontemporal_store(tl, (v2f*)(sgb + 4094)); }
    } else {
        for (int k = tid; k < nb * 10; k += 256)
            __builtin_nontemporal_store(semb[k], egb + k);
        for (int k = tid; k < nb * 16; k += 256)
            __builtin_nontemporal_store(ssh[k + (k >> 4)], sgb + k);
    }
}

extern "C" void kernel_launch(void* const* d_in, const int* in_sizes, int n_in,
                              void* d_out, int out_size, void* d_ws, size_t ws_size,
                              hipStream_t stream) {
    const float* pos  = (const float*)d_in[0];
    const float* qpos = (const float*)d_in[1];
    const float* feat = (const float*)d_in[2];
    const int*   esrc = (const int*)d_in[3];
    const int*   edst = (const int*)d_in[4];
    float* out = (float*)d_out;

    const int Ftot = in_sizes[2];          // 320000
    const int E    = in_sizes[3];          // 3000000
    const int Nx   = in_sizes[0] / 3;      // 5000
    const int Nq   = in_sizes[1] / 3;      // 10000

    const unsigned long long OFF_FEAT = 2;
    const unsigned long long OFF_SRC  = OFF_FEAT + (unsigned long long)Ftot;
    const unsigned long long OFF_DST  = OFF_SRC + (unsigned long long)E;
    const unsigned long long OFF_EMB  = OFF_DST + (unsigned long long)E;
    const unsigned long long OFF_SH   = OFF_EMB + 10ULL * E;
    const unsigned long long OFF_LEN  = OFF_SH  + 16ULL * E;

    const int n2feat    = Ftot / 2;
    const int nblk_edge = (E + 255) / 256;
    const int nblk_feat = (n2feat + 255) / 256;

    const size_t ws_need = (size_t)(Nx + Nq) * 16;
    if (ws_size >= ws_need) {
        float* wp = (float*)d_ws;
        int n = Nx + Nq;
        pack_kernel<<<(n + 255) / 256, 256, 0, stream>>>(pos, qpos, wp, Nx, Nq);
        fused_kernel<true><<<nblk_edge + nblk_feat, 256, 0, stream>>>(
            wp, wp + 4 * (size_t)Nx, feat, esrc, edst, out,
            E, nblk_edge, n2feat, OFF_SRC, OFF_DST, OFF_EMB, OFF_SH, OFF_LEN);
    } else {
        fused_kernel<false><<<nblk_edge + nblk_feat, 256, 0, stream>>>(
            pos, qpos, feat, esrc, edst, out,
            E, nblk_edge, n2feat, OFF_SRC, OFF_DST, OFF_EMB, OFF_SH, OFF_LEN);
    }
}